// Round 5
// baseline (145.590 us; speedup 1.0000x reference)
//
#include <hip/hip_runtime.h>
#include <math.h>

#define N_POS 8192
#define FEAT 512
#define NTOT (2 * N_POS)
#define BM 256
#define BN 256
#define NT 8   // K-tiles of 64

typedef __attribute__((ext_vector_type(8))) short bf16x8;
typedef __attribute__((ext_vector_type(4))) short s16x4;
typedef __attribute__((ext_vector_type(4))) float f32x4;

__device__ inline unsigned long long packMax(float v, unsigned idx) {
    unsigned u = __float_as_uint(v);
    u = (u & 0x80000000u) ? ~u : (u | 0x80000000u);
    return ((unsigned long long)u << 32) | (unsigned)(~idx);
}
__device__ inline unsigned unpackIdx(unsigned long long p) {
    return ~(unsigned)(p & 0xffffffffull);
}
__device__ inline short f2bf(float f) {
    unsigned u = __float_as_uint(f);
    return (short)((u + 0x7FFFu + ((u >> 16) & 1u)) >> 16);
}

// gather rows by idx, convert fp32 -> bf16 (RNE); also zero the argmax buffers
__global__ __launch_bounds__(256) void gather_convert2(
    const float* __restrict__ F0, const int* __restrict__ idx0, short* __restrict__ out0,
    const float* __restrict__ F1, const int* __restrict__ idx1, short* __restrict__ out1,
    unsigned long long* __restrict__ zbuf)
{
    if (blockIdx.x < 64) zbuf[blockIdx.x * 256 + threadIdx.x] = 0ull;
    const int per = N_POS * FEAT / 4;
    int t = blockIdx.x * 256 + threadIdx.x;
    const float* F; const int* idx; short* out;
    if (t < per) { F = F0; idx = idx0; out = out0; }
    else         { F = F1; idx = idx1; out = out1; t -= per; }
    int i  = t >> 7;
    int k4 = t & 127;
    float4 v = *(const float4*)(F + (size_t)idx[i] * FEAT + k4 * 4);
    s16x4 o = { f2bf(v.x), f2bf(v.y), f2bf(v.z), f2bf(v.w) };
    *(s16x4*)(out + (size_t)i * FEAT + k4 * 4) = o;
}

// LDS row = 64 bf16 = 8 chunks of 16B; chunk c of row r stored at slot c^(r&7)
__device__ inline bf16x8 frag(const short* S, int row, int chunk) {
    int c = chunk ^ (row & 7);
    return *(const bf16x8*)((const char*)S + row * 128 + c * 16);
}

__global__ __launch_bounds__(512, 2) void gemm_bf16_argmax(
    const short* __restrict__ Abf, const short* __restrict__ Bbf,
    unsigned long long* __restrict__ row_best,
    unsigned long long* __restrict__ col_best)
{
    __shared__ __align__(16) short As[2][BM][64];   // 2 x 32 KB
    __shared__ __align__(16) short Bs[2][BN][64];   // 2 x 32 KB
    __shared__ unsigned long long redR[BM], redC[BN];  // 4 KB -> 132 KB total, 1 blk/CU

    const int tid  = threadIdx.x;
    const int lane = tid & 63;
    const int w    = tid >> 6;          // 8 waves
    const int wm   = w >> 2;            // 0..1 : 128-row half
    const int wn   = w & 3;             // 0..3 : 64-col quarter
    const int l15  = lane & 15, kh = lane >> 4;

    // XCD-aware 2-level swizzle: 1024 blocks, 8 XCDs, 32x32 tile grid
    const int bid = blockIdx.x;
    const int xcd = bid & 7;
    const int loc = bid >> 3;           // 0..127
    const int cg  = loc >> 4;           // 0..7 : col-group of 4
    const int r4  = (loc & 15) >> 2;    // 0..3
    const int c4  = loc & 3;            // 0..3
    const int brow = (xcd * 4 + r4) * BM;
    const int bcol = (cg * 4 + c4) * BN;

    if (tid < BM) redR[tid] = 0ull; else redC[tid - BM] = 0ull;

    const int srow = lane >> 3;             // 0..7
    const int scp  = (lane & 7) ^ srow;     // pre-swizzled source chunk

    // one STAGE = 8 KB: 8 waves x 8 rows each, 16B/lane, linear LDS dest
#define STAGE8K(gptr, gRowBase, ldsPtr, lRowBase, t)                                        \
    __builtin_amdgcn_global_load_lds(                                                       \
        (const __attribute__((address_space(1))) unsigned int*)                             \
            ((gptr) + (size_t)((gRowBase) + srow) * FEAT + (t) * 64 + scp * 8),             \
        (__attribute__((address_space(3))) unsigned int*)                                   \
            ((char*)(ldsPtr) + (lRowBase) * 128 + lane * 16),                               \
        16, 0, 0)

    // region row-bases (per wave w)
    const int aLo0 = w * 8,                 aLo1 = 128 + w * 8;    // A rows read by m0-3
    const int aHi0 = 64 + w * 8,            aHi1 = 192 + w * 8;    // A rows read by m4-7
    const int bLo0 = (w & 3) * 8 + (w >> 2) * 64, bLo1 = bLo0 + 128;  // B rows read by n0-1
    const int bHi0 = bLo0 + 32,             bHi1 = bLo0 + 160;     // B rows read by n2-3

#define ST_ALO(bf, t) { STAGE8K(Abf, brow + aLo0, &As[bf][0][0], aLo0, t); \
                        STAGE8K(Abf, brow + aLo1, &As[bf][0][0], aLo1, t); }
#define ST_AHI(bf, t) { STAGE8K(Abf, brow + aHi0, &As[bf][0][0], aHi0, t); \
                        STAGE8K(Abf, brow + aHi1, &As[bf][0][0], aHi1, t); }
#define ST_BLO(bf, t) { STAGE8K(Bbf, bcol + bLo0, &Bs[bf][0][0], bLo0, t); \
                        STAGE8K(Bbf, bcol + bLo1, &Bs[bf][0][0], bLo1, t); }
#define ST_BHI(bf, t) { STAGE8K(Bbf, bcol + bHi0, &Bs[bf][0][0], bHi0, t); \
                        STAGE8K(Bbf, bcol + bHi1, &Bs[bf][0][0], bHi1, t); }

    f32x4 acc[8][4];
    #pragma unroll
    for (int m = 0; m < 8; ++m)
        #pragma unroll
        for (int n = 0; n < 4; ++n)
            acc[m][n] = (f32x4)0.f;

    bf16x8 al[4][2], ah[4][2], bl[2][2], bh[2][2];

#define RD_AL(bf) _Pragma("unroll") for (int mi = 0; mi < 4; ++mi) _Pragma("unroll") for (int kb = 0; kb < 2; ++kb) \
    al[mi][kb] = frag(&As[bf][0][0], wm * 128 + mi * 16 + l15, kb * 4 + kh);
#define RD_AH(bf) _Pragma("unroll") for (int mi = 0; mi < 4; ++mi) _Pragma("unroll") for (int kb = 0; kb < 2; ++kb) \
    ah[mi][kb] = frag(&As[bf][0][0], wm * 128 + 64 + mi * 16 + l15, kb * 4 + kh);
#define RD_BL(bf) _Pragma("unroll") for (int nn = 0; nn < 2; ++nn) _Pragma("unroll") for (int kb = 0; kb < 2; ++kb) \
    bl[nn][kb] = frag(&Bs[bf][0][0], wn * 64 + nn * 16 + l15, kb * 4 + kh);
#define RD_BH(bf) _Pragma("unroll") for (int nn = 0; nn < 2; ++nn) _Pragma("unroll") for (int kb = 0; kb < 2; ++kb) \
    bh[nn][kb] = frag(&Bs[bf][0][0], wn * 64 + 32 + nn * 16 + l15, kb * 4 + kh);

#define MFMA16(AARR, mq, BARR, nh)                                                          \
    __builtin_amdgcn_s_setprio(1);                                                          \
    _Pragma("unroll") for (int mi = 0; mi < 4; ++mi)                                        \
    _Pragma("unroll") for (int nn = 0; nn < 2; ++nn)                                        \
    _Pragma("unroll") for (int kb = 0; kb < 2; ++kb)                                        \
        acc[(mq)*4+mi][(nh)*2+nn] = __builtin_amdgcn_mfma_f32_16x16x32_bf16(                \
            AARR[mi][kb], BARR[nn][kb], acc[(mq)*4+mi][(nh)*2+nn], 0, 0, 0);                \
    __builtin_amdgcn_s_setprio(0);

#define WAIT_LGKM  asm volatile("s_waitcnt lgkmcnt(0)" ::: "memory"); __builtin_amdgcn_sched_barrier(0);
#define BAR        __builtin_amdgcn_s_barrier();

    // ---- prologue: T0 fully + A-low(T1); leave A-low(T1) pair in flight ----
    ST_ALO(0, 0); ST_AHI(0, 0); ST_BLO(0, 0); ST_BHI(0, 0);
    ST_ALO(1, 1);
    asm volatile("s_waitcnt vmcnt(2)" ::: "memory");
    BAR;

    for (int t = 0; t < NT; ++t) {
        const int buf = t & 1, nb = buf ^ 1;
        // phase 0: read A-low + B-low; issue A-high(t+1)
        RD_AL(buf); RD_BL(buf);
        if (t + 1 < NT) ST_AHI(nb, t + 1);
        BAR; WAIT_LGKM;
        MFMA16(al, 0, bl, 0);
        BAR;
        // phase 1: read B-high; issue B-low(t+1)
        RD_BH(buf);
        if (t + 1 < NT) ST_BLO(nb, t + 1);
        BAR; WAIT_LGKM;
        MFMA16(al, 0, bh, 1);
        BAR;
        // phase 2: read A-high; issue B-high(t+1)
        RD_AH(buf);
        if (t + 1 < NT) ST_BHI(nb, t + 1);
        BAR; WAIT_LGKM;
        MFMA16(ah, 1, bl, 0);
        BAR;
        // phase 3: issue A-low(t+2) into SAME buf; counted drain covers all of t+1
        if (t + 2 < NT) {
            ST_ALO(buf, t + 2);
            asm volatile("s_waitcnt vmcnt(2)" ::: "memory");
        } else {
            asm volatile("s_waitcnt vmcnt(0)" ::: "memory");
        }
        BAR;
        MFMA16(ah, 1, bh, 1);
        BAR;
    }

    // ---- fused argmax epilogue ----
    // lane holds C[row = wm*128 + m*16 + kh*4 + j][col = wn*64 + n*16 + l15]
    #pragma unroll
    for (int m = 0; m < 8; ++m) {
        #pragma unroll
        for (int j = 0; j < 4; ++j) {
            float best = acc[m][0][j]; int bn_ = 0;
            #pragma unroll
            for (int n = 1; n < 4; ++n)
                if (acc[m][n][j] > best) { best = acc[m][n][j]; bn_ = n; }
            unsigned long long p = packMax(best, (unsigned)(bcol + wn * 64 + bn_ * 16 + l15));
            #pragma unroll
            for (int mask = 1; mask <= 8; mask <<= 1) {
                unsigned long long q = __shfl_xor(p, mask);
                if (q > p) p = q;
            }
            if (l15 == 0)
                atomicMax(&redR[wm * 128 + m * 16 + kh * 4 + j], p);
        }
    }
    #pragma unroll
    for (int n = 0; n < 4; ++n) {
        float best = acc[0][n][0]; int bm_ = 0, bj_ = 0;
        #pragma unroll
        for (int m = 0; m < 8; ++m)
            #pragma unroll
            for (int j = 0; j < 4; ++j)
                if (acc[m][n][j] > best) { best = acc[m][n][j]; bm_ = m; bj_ = j; }
        unsigned long long p = packMax(best, (unsigned)(brow + wm * 128 + bm_ * 16 + kh * 4 + bj_));
        #pragma unroll
        for (int mask = 16; mask <= 32; mask <<= 1) {
            unsigned long long q = __shfl_xor(p, mask);
            if (q > p) p = q;
        }
        if (kh == 0)
            atomicMax(&redC[wn * 64 + n * 16 + l15], p);
    }
    __syncthreads();
    if (tid < BM) atomicMax(&row_best[brow + tid], redR[tid]);
    else          atomicMax(&col_best[bcol + tid - BM], redC[tid - BM]);
}

__global__ __launch_bounds__(1024) void finalize_loss(
    const float* __restrict__ T4,
    const float* __restrict__ src_points, const float* __restrict__ tgt_points,
    const float* __restrict__ src_scores, const float* __restrict__ tgt_scores,
    const int* __restrict__ sidx, const int* __restrict__ tidx,
    const unsigned long long* __restrict__ row_best,
    const unsigned long long* __restrict__ col_best,
    float* __restrict__ out)
{
    const int tid = threadIdx.x;
    const float R00=T4[0],R01=T4[1],R02=T4[2],t0=T4[3];
    const float R10=T4[4],R11=T4[5],R12=T4[6],t1=T4[7];
    const float R20=T4[8],R21=T4[9],R22=T4[10],t2=T4[11];

    // batched gather phases: 16 independent chains -> wide MLP instead of pointer-chase
    unsigned nn[16];
    #pragma unroll
    for (int u = 0; u < 16; ++u) {
        int i = tid + u * 1024;
        nn[u] = unpackIdx(i < N_POS ? row_best[i] : col_best[i - N_POS]);
    }
    int sI[16], tI[16];
    #pragma unroll
    for (int u = 0; u < 16; ++u) {
        int i = tid + u * 1024;
        if (i < N_POS) { sI[u] = sidx[i];     tI[u] = tidx[nn[u]]; }
        else           { sI[u] = sidx[nn[u]]; tI[u] = tidx[i - N_POS]; }
    }
    float sc[16];
    #pragma unroll
    for (int u = 0; u < 16; ++u) {
        int i = tid + u * 1024;
        sc[u] = (i < N_POS) ? src_scores[sI[u]] : tgt_scores[tI[u]];
    }
    float spx[16], spy[16], spz[16], tpx[16], tpy[16], tpz[16];
    #pragma unroll
    for (int u = 0; u < 16; ++u) {
        const float* p = src_points + (size_t)sI[u] * 3;
        spx[u] = p[0]; spy[u] = p[1]; spz[u] = p[2];
        const float* q = tgt_points + (size_t)tI[u] * 3;
        tpx[u] = q[0]; tpy[u] = q[1]; tpz[u] = q[2];
    }

    double S1 = 0.0, S0 = 0.0;
    float cnt = 0.f, sumres = 0.f, corr = 0.f;
    #pragma unroll
    for (int u = 0; u < 16; ++u) {
        float px = R00*spx[u]+R01*spy[u]+R02*spz[u]+t0;
        float py = R10*spx[u]+R11*spy[u]+R12*spz[u]+t1;
        float pz = R20*spx[u]+R21*spy[u]+R22*spz[u]+t2;
        float dx = px-tpx[u], dy = py-tpy[u], dz = pz-tpz[u];
        float label = (sqrtf(dx*dx+dy*dy+dz*dz) < 0.1f) ? 1.f : 0.f;
        cnt += label;
        float res = (sc[u] > 0.5f) ? 1.f : 0.f;
        sumres += res;
        corr += res * label;
        if (label > 0.5f) S1 += (double)(-logf(sc[u]));
        else              S0 += (double)(-logf(1.0f - sc[u]));
    }

    #pragma unroll
    for (int off = 32; off > 0; off >>= 1) {
        S1 += __shfl_down(S1, off);
        S0 += __shfl_down(S0, off);
        cnt += __shfl_down(cnt, off);
        sumres += __shfl_down(sumres, off);
        corr += __shfl_down(corr, off);
    }
    __shared__ double sh1[16], sh0[16];
    __shared__ float shc[16], shr[16], shco[16];
    int wid = tid >> 6, lane = tid & 63;
    if (lane == 0) { sh1[wid]=S1; sh0[wid]=S0; shc[wid]=cnt; shr[wid]=sumres; shco[wid]=corr; }
    __syncthreads();
    if (tid == 0) {
        double s1 = 0, s0 = 0; float c = 0, rr = 0, co = 0;
        for (int v = 0; v < 16; ++v) { s1+=sh1[v]; s0+=sh0[v]; c+=shc[v]; rr+=shr[v]; co+=shco[v]; }
        float nw = c / (float)NTOT;
        float loss = (float)((nw * s1 + (1.0 - (double)nw) * s0) / (double)NTOT);
        out[0] = loss;
        out[1] = co / (rr + 1e-12f);
        out[2] = co / (c + 1e-12f);
    }
}

extern "C" void kernel_launch(void* const* d_in, const int* in_sizes, int n_in,
                              void* d_out, int out_size, void* d_ws, size_t ws_size,
                              hipStream_t stream) {
    const float* T4         = (const float*)d_in[0];
    const float* src_points = (const float*)d_in[1];
    const float* tgt_points = (const float*)d_in[2];
    const float* src_scores = (const float*)d_in[3];
    const float* tgt_scores = (const float*)d_in[4];
    const float* src_feats  = (const float*)d_in[5];
    const float* tgt_feats  = (const float*)d_in[6];
    const int*   sidx       = (const int*)d_in[7];
    const int*   tidx       = (const int*)d_in[8];

    unsigned long long* row_best = (unsigned long long*)d_ws;
    unsigned long long* col_best = row_best + N_POS;
    short* Abf = (short*)((char*)d_ws + 2 * N_POS * sizeof(unsigned long long));
    short* Bbf = Abf + (size_t)N_POS * FEAT;
    float* out = (float*)d_out;

    hipLaunchKernelGGL(gather_convert2, dim3(2 * N_POS * FEAT / 4 / 256), dim3(256), 0, stream,
                       src_feats, sidx, Abf, tgt_feats, tidx, Bbf, row_best);
    hipLaunchKernelGGL(gemm_bf16_argmax, dim3((N_POS / BM) * (N_POS / BN)), dim3(512), 0, stream,
                       Abf, Bbf, row_best, col_best);
    hipLaunchKernelGGL(finalize_loss, dim3(1), dim3(1024), 0, stream,
                       T4, src_points, tgt_points, src_scores, tgt_scores,
                       sidx, tidx, row_best, col_best, out);
}

// Round 6
// 141.924 us; speedup vs baseline: 1.0258x; 1.0258x over previous
//
#include <hip/hip_runtime.h>
#include <math.h>

#define N_POS 8192
#define FEAT 512
#define NTOT (2 * N_POS)
#define BM 128
#define BN 128
#define NSTEP 16   // K-steps of 32

#define AS1 __attribute__((address_space(1)))
#define AS3 __attribute__((address_space(3)))

typedef __attribute__((ext_vector_type(8))) short bf16x8;
typedef __attribute__((ext_vector_type(4))) short s16x4;
typedef __attribute__((ext_vector_type(4))) float f32x4;

__device__ inline unsigned long long packMax(float v, unsigned idx) {
    unsigned u = __float_as_uint(v);
    u = (u & 0x80000000u) ? ~u : (u | 0x80000000u);
    return ((unsigned long long)u << 32) | (unsigned)(~idx);
}
__device__ inline unsigned unpackIdx(unsigned long long p) {
    return ~(unsigned)(p & 0xffffffffull);
}
__device__ inline short f2bf(float f) {
    unsigned u = __float_as_uint(f);
    return (short)((u + 0x7FFFu + ((u >> 16) & 1u)) >> 16);
}

// gather rows by idx, convert fp32 -> bf16 (RNE); also zero the argmax buffers
__global__ __launch_bounds__(256) void gather_convert2(
    const float* __restrict__ F0, const int* __restrict__ idx0, short* __restrict__ out0,
    const float* __restrict__ F1, const int* __restrict__ idx1, short* __restrict__ out1,
    unsigned long long* __restrict__ zbuf)
{
    if (blockIdx.x < 64) zbuf[blockIdx.x * 256 + threadIdx.x] = 0ull;
    const int per = N_POS * FEAT / 4;
    int t = blockIdx.x * 256 + threadIdx.x;
    const float* F; const int* idx; short* out;
    if (t < per) { F = F0; idx = idx0; out = out0; }
    else         { F = F1; idx = idx1; out = out1; t -= per; }
    int i  = t >> 7;
    int k4 = t & 127;
    float4 v = *(const float4*)(F + (size_t)idx[i] * FEAT + k4 * 4);
    s16x4 o = { f2bf(v.x), f2bf(v.y), f2bf(v.z), f2bf(v.w) };
    *(s16x4*)(out + (size_t)i * FEAT + k4 * 4) = o;
}

// ---- pair-row LDS layout, BK=32 ----
// LDS line l (128 B) holds rows {2l, 2l+1}: packed slot p = (r&1)*4 + kchunk,
// stored at slot s = p ^ (l&7). Read of 16 rows x fixed kchunk = 2 lanes per
// 4-bank group per 16-lane phase -> conflict-free.
__device__ inline bf16x8 fragP(const short* S, int row, int kh) {
    int line = row >> 1;
    int slot = (((row & 1) << 2) | kh) ^ (line & 7);
    return *(const bf16x8*)((const char*)S + line * 128 + slot * 16);
}

__global__ __launch_bounds__(256, 4) void gemm_bf16_argmax(
    const short* __restrict__ Abf, const short* __restrict__ Bbf,
    unsigned long long* __restrict__ row_best,
    unsigned long long* __restrict__ col_best)
{
    __shared__ __align__(16) short As[2][64 * 64];   // 2 x 8 KB (64 lines x 128 B)
    __shared__ __align__(16) short Bs[2][64 * 64];   // 2 x 8 KB
    __shared__ unsigned long long redR[BM], redC[BN]; // 4 KB -> 36.9 KB, 4 blocks/CU

    const int tid  = threadIdx.x;
    const int lane = tid & 63;
    const int w    = tid >> 6;          // 4 waves
    const int wm   = w >> 1, wn = w & 1;
    const int l15  = lane & 15, kh = lane >> 4;

    // 2-level XCD swizzle (round-4): slab of 8 block-rows, walked in 4-col groups
    const int bid  = blockIdx.x;
    const int xcd  = bid & 7;
    const int loc  = bid >> 3;
    const int cg   = loc >> 5;
    const int r8   = (loc & 31) >> 2;
    const int c4   = loc & 3;
    const int brow = (xcd * 8 + r8) * BM;
    const int bcol = (cg * 4 + c4) * BN;

    if (tid < BM) redR[tid] = 0ull; else redC[tid - BM] = 0ull;

    // staging decode (pair-row inverse permutation), constant per lane:
    // issue covers 8 lines; lane -> line = Lbase + (lane>>3), slot = lane&7
    // content packed p = slot ^ (lineOff&7); global row = line*2 + (p>>2), chunk = p&3
    const int iLoc   = lane >> 3;            // 0..7 line offset (Lbase multiple of 8)
    const int p      = (lane & 7) ^ iLoc;    // packed index
    const int rowOff = iLoc * 2 + (p >> 2);  // 0..15 row within 16-row group
    const int colOff = (p & 3) * 8;          // shorts within 32-k row

    // wave w stages rows w*32..w*32+31 of A and B (2 issues each of 8 lines)
#define STAGE(buf, t)                                                                     \
    {                                                                                     \
        _Pragma("unroll")                                                                 \
        for (int u = 0; u < 2; ++u) {                                                     \
            __builtin_amdgcn_global_load_lds(                                             \
                (const AS1 unsigned int*)(Abf +                                           \
                    (size_t)(brow + w * 32 + u * 16 + rowOff) * FEAT + (t) * 32 + colOff),\
                (AS3 unsigned int*)((char*)&As[buf][0] + w * 2048 + u * 1024 + lane * 16),\
                16, 0, 0);                                                                \
            __builtin_amdgcn_global_load_lds(                                             \
                (const AS1 unsigned int*)(Bbf +                                           \
                    (size_t)(bcol + w * 32 + u * 16 + rowOff) * FEAT + (t) * 32 + colOff),\
                (AS3 unsigned int*)((char*)&Bs[buf][0] + w * 2048 + u * 1024 + lane * 16),\
                16, 0, 0);                                                                \
        }                                                                                 \
    }

    f32x4 acc[4][4];
    #pragma unroll
    for (int m = 0; m < 4; ++m)
        #pragma unroll
        for (int n = 0; n < 4; ++n)
            acc[m][n] = (f32x4)0.f;

    STAGE(0, 0);
    __syncthreads();   // prologue drain (only exposed latency in the kernel)

    for (int t = 0; t < NSTEP; ++t) {
        const int cur = t & 1;
        if (t + 1 < NSTEP) STAGE(cur ^ 1, t + 1);   // issue BEFORE compute: latency
                                                    // hides under the 16 MFMAs below
        bf16x8 a[4], b[4];
        #pragma unroll
        for (int i = 0; i < 4; ++i) {
            a[i] = fragP(&As[cur][0], wm * 64 + i * 16 + l15, kh);
            b[i] = fragP(&Bs[cur][0], wn * 64 + i * 16 + l15, kh);
        }
        #pragma unroll
        for (int m = 0; m < 4; ++m)
            #pragma unroll
            for (int n = 0; n < 4; ++n)
                acc[m][n] = __builtin_amdgcn_mfma_f32_16x16x32_bf16(a[m], b[n], acc[m][n], 0, 0, 0);
        __syncthreads();   // drains vmcnt(0): stage loads issued ~400 cyc ago -> cheap
    }
#undef STAGE

    // ---- fused argmax epilogue (verified mapping) ----
    // lane holds C[row = wm*64 + m*16 + kh*4 + j][col = wn*64 + n*16 + l15]
    #pragma unroll
    for (int m = 0; m < 4; ++m) {
        #pragma unroll
        for (int j = 0; j < 4; ++j) {
            float best = acc[m][0][j]; int bn_ = 0;
            #pragma unroll
            for (int n = 1; n < 4; ++n)
                if (acc[m][n][j] > best) { best = acc[m][n][j]; bn_ = n; }
            unsigned long long pk = packMax(best, (unsigned)(bcol + wn * 64 + bn_ * 16 + l15));
            #pragma unroll
            for (int mask = 1; mask <= 8; mask <<= 1) {
                unsigned long long q = __shfl_xor(pk, mask);
                if (q > pk) pk = q;
            }
            if (l15 == 0)
                atomicMax(&redR[wm * 64 + m * 16 + kh * 4 + j], pk);
        }
    }
    #pragma unroll
    for (int n = 0; n < 4; ++n) {
        float best = acc[0][n][0]; int bm_ = 0, bj_ = 0;
        #pragma unroll
        for (int m = 0; m < 4; ++m)
            #pragma unroll
            for (int j = 0; j < 4; ++j)
                if (acc[m][n][j] > best) { best = acc[m][n][j]; bm_ = m; bj_ = j; }
        unsigned long long pk = packMax(best, (unsigned)(brow + wm * 64 + bm_ * 16 + kh * 4 + bj_));
        #pragma unroll
        for (int mask = 16; mask <= 32; mask <<= 1) {
            unsigned long long q = __shfl_xor(pk, mask);
            if (q > pk) pk = q;
        }
        if (kh == 0)
            atomicMax(&redC[wn * 64 + n * 16 + l15], pk);
    }
    __syncthreads();
    if (tid < BM) atomicMax(&row_best[brow + tid], redR[tid]);
    else          atomicMax(&col_best[bcol + tid - BM], redC[tid - BM]);
}

__global__ __launch_bounds__(1024) void finalize_loss(
    const float* __restrict__ T4,
    const float* __restrict__ src_points, const float* __restrict__ tgt_points,
    const float* __restrict__ src_scores, const float* __restrict__ tgt_scores,
    const int* __restrict__ sidx, const int* __restrict__ tidx,
    const unsigned long long* __restrict__ row_best,
    const unsigned long long* __restrict__ col_best,
    float* __restrict__ out)
{
    const int tid = threadIdx.x;
    const float R00=T4[0],R01=T4[1],R02=T4[2],t0=T4[3];
    const float R10=T4[4],R11=T4[5],R12=T4[6],t1=T4[7];
    const float R20=T4[8],R21=T4[9],R22=T4[10],t2=T4[11];

    unsigned nn[16];
    #pragma unroll
    for (int u = 0; u < 16; ++u) {
        int i = tid + u * 1024;
        nn[u] = unpackIdx(i < N_POS ? row_best[i] : col_best[i - N_POS]);
    }
    int sI[16], tI[16];
    #pragma unroll
    for (int u = 0; u < 16; ++u) {
        int i = tid + u * 1024;
        if (i < N_POS) { sI[u] = sidx[i];     tI[u] = tidx[nn[u]]; }
        else           { sI[u] = sidx[nn[u]]; tI[u] = tidx[i - N_POS]; }
    }
    float sc[16];
    #pragma unroll
    for (int u = 0; u < 16; ++u) {
        int i = tid + u * 1024;
        sc[u] = (i < N_POS) ? src_scores[sI[u]] : tgt_scores[tI[u]];
    }
    float spx[16], spy[16], spz[16], tpx[16], tpy[16], tpz[16];
    #pragma unroll
    for (int u = 0; u < 16; ++u) {
        const float* p = src_points + (size_t)sI[u] * 3;
        spx[u] = p[0]; spy[u] = p[1]; spz[u] = p[2];
        const float* q = tgt_points + (size_t)tI[u] * 3;
        tpx[u] = q[0]; tpy[u] = q[1]; tpz[u] = q[2];
    }

    double S1 = 0.0, S0 = 0.0;
    float cnt = 0.f, sumres = 0.f, corr = 0.f;
    #pragma unroll
    for (int u = 0; u < 16; ++u) {
        float px = R00*spx[u]+R01*spy[u]+R02*spz[u]+t0;
        float py = R10*spx[u]+R11*spy[u]+R12*spz[u]+t1;
        float pz = R20*spx[u]+R21*spy[u]+R22*spz[u]+t2;
        float dx = px-tpx[u], dy = py-tpy[u], dz = pz-tpz[u];
        float label = (sqrtf(dx*dx+dy*dy+dz*dz) < 0.1f) ? 1.f : 0.f;
        cnt += label;
        float res = (sc[u] > 0.5f) ? 1.f : 0.f;
        sumres += res;
        corr += res * label;
        if (label > 0.5f) S1 += (double)(-logf(sc[u]));
        else              S0 += (double)(-logf(1.0f - sc[u]));
    }

    #pragma unroll
    for (int off = 32; off > 0; off >>= 1) {
        S1 += __shfl_down(S1, off);
        S0 += __shfl_down(S0, off);
        cnt += __shfl_down(cnt, off);
        sumres += __shfl_down(sumres, off);
        corr += __shfl_down(corr, off);
    }
    __shared__ double sh1[16], sh0[16];
    __shared__ float shc[16], shr[16], shco[16];
    int wid = tid >> 6, lane = tid & 63;
    if (lane == 0) { sh1[wid]=S1; sh0[wid]=S0; shc[wid]=cnt; shr[wid]=sumres; shco[wid]=corr; }
    __syncthreads();
    if (tid == 0) {
        double s1 = 0, s0 = 0; float c = 0, rr = 0, co = 0;
        for (int v = 0; v < 16; ++v) { s1+=sh1[v]; s0+=sh0[v]; c+=shc[v]; rr+=shr[v]; co+=shco[v]; }
        float nw = c / (float)NTOT;
        float loss = (float)((nw * s1 + (1.0 - (double)nw) * s0) / (double)NTOT);
        out[0] = loss;
        out[1] = co / (rr + 1e-12f);
        out[2] = co / (c + 1e-12f);
    }
}

extern "C" void kernel_launch(void* const* d_in, const int* in_sizes, int n_in,
                              void* d_out, int out_size, void* d_ws, size_t ws_size,
                              hipStream_t stream) {
    const float* T4         = (const float*)d_in[0];
    const float* src_points = (const float*)d_in[1];
    const float* tgt_points = (const float*)d_in[2];
    const float* src_scores = (const float*)d_in[3];
    const float* tgt_scores = (const float*)d_in[4];
    const float* src_feats  = (const float*)d_in[5];
    const float* tgt_feats  = (const float*)d_in[6];
    const int*   sidx       = (const int*)d_in[7];
    const int*   tidx       = (const int*)d_in[8];

    unsigned long long* row_best = (unsigned long long*)d_ws;
    unsigned long long* col_best = row_best + N_POS;
    short* Abf = (short*)((char*)d_ws + 2 * N_POS * sizeof(unsigned long long));
    short* Bbf = Abf + (size_t)N_POS * FEAT;
    float* out = (float*)d_out;

    hipLaunchKernelGGL(gather_convert2, dim3(2 * N_POS * FEAT / 4 / 256), dim3(256), 0, stream,
                       src_feats, sidx, Abf, tgt_feats, tidx, Bbf, row_best);
    hipLaunchKernelGGL(gemm_bf16_argmax, dim3((N_POS / BM) * (N_POS / BN)), dim3(256), 0, stream,
                       Abf, Bbf, row_best, col_best);
    hipLaunchKernelGGL(finalize_loss, dim3(1), dim3(1024), 0, stream,
                       T4, src_points, tgt_points, src_scores, tgt_scores,
                       sidx, tidx, row_best, col_best, out);
}